// Round 4
// baseline (462.973 us; speedup 1.0000x reference)
//
#include <hip/hip_runtime.h>

#define Bc 2
#define Sc 2048
#define Dc 2048
#define Hc 16
#define DHc 128

typedef _Float16 f16;
typedef __attribute__((ext_vector_type(4))) _Float16 v4h;
typedef __attribute__((ext_vector_type(8))) _Float16 v8h;
typedef __attribute__((ext_vector_type(4))) float v4f;
typedef __attribute__((ext_vector_type(16))) float v16f;
typedef __attribute__((ext_vector_type(4))) float f32x4;

// ---------------------------------------------------------------------------
// Convert f32 inputs -> f16 once.
// ---------------------------------------------------------------------------
__global__ void cvt_kernel(const float* __restrict__ x, const float* __restrict__ wq,
                           const float* __restrict__ wk, const float* __restrict__ wv,
                           f16* __restrict__ xh, f16* __restrict__ wqh,
                           f16* __restrict__ wkh, f16* __restrict__ wvh)
{
    int bid = blockIdx.x;
    const float* src; f16* dst; int idx;
    if (bid < 8192)       { src = x;  dst = xh;  idx = bid; }
    else if (bid < 12288) { src = wq; dst = wqh; idx = bid - 8192; }
    else if (bid < 16384) { src = wk; dst = wkh; idx = bid - 12288; }
    else                  { src = wv; dst = wvh; idx = bid - 16384; }
    int i = idx * 256 + threadIdx.x;
    f32x4 v = ((const f32x4*)src)[i];
    v4h hv; hv[0]=(f16)v[0]; hv[1]=(f16)v[1]; hv[2]=(f16)v[2]; hv[3]=(f16)v[3];
    ((v4h*)dst)[i] = hv;
}

// ---------------------------------------------------------------------------
// f16 projection GEMM (global_load_lds width=16) with RoPE fused into the
// epilogue for z<2. z: 0->Q (roped+scaled), 1->K (roped), 2->V^T [dh][s].
// ---------------------------------------------------------------------------
__launch_bounds__(256)
__global__ void proj_f16_kernel(const f16* __restrict__ xh, const f16* __restrict__ wqh,
                                const f16* __restrict__ wkh, const f16* __restrict__ wvh,
                                const float* __restrict__ cs, const float* __restrict__ sn,
                                f16* __restrict__ qh, f16* __restrict__ kh,
                                f16* __restrict__ vt)
{
    const int z = blockIdx.z;
    const f16* wh = (z == 0) ? wqh : ((z == 1) ? wkh : wvh);
    const int m0 = blockIdx.x * 128, n0 = blockIdx.y * 128;
    const int tid = threadIdx.x, lane = tid & 63, wid = tid >> 6;
    const int wm = wid >> 1, wn = wid & 1;
    const int l15 = lane & 15, quad = lane >> 4;
    const int lrow = lane >> 3, lcol = lane & 7;

    __shared__ __align__(16) f16 smem[128 * 136];
    f16 (*As)[64] = (f16(*)[64])smem;
    f16 (*Bs)[64] = (f16(*)[64])(smem + 8192);

    v4f acc[4][4];
    #pragma unroll
    for (int i = 0; i < 4; ++i)
        #pragma unroll
        for (int j = 0; j < 4; ++j)
            acc[i][j] = (v4f){0.f, 0.f, 0.f, 0.f};

    for (int k0 = 0; k0 < Dc; k0 += 64) {
        __syncthreads();
        #pragma unroll
        for (int i = 0; i < 4; ++i) {
            int g = wid * 4 + i;
            const f16* ga = xh + (size_t)(m0 + g * 8 + lrow) * Dc + k0 + lcol * 8;
            __builtin_amdgcn_global_load_lds(
                (const __attribute__((address_space(1))) void*)ga,
                (__attribute__((address_space(3))) void*)(smem + g * 512), 16, 0, 0);
            const f16* gb = wh + (size_t)(n0 + g * 8 + lrow) * Dc + k0 + lcol * 8;
            __builtin_amdgcn_global_load_lds(
                (const __attribute__((address_space(1))) void*)gb,
                (__attribute__((address_space(3))) void*)(smem + 8192 + g * 512), 16, 0, 0);
        }
        __syncthreads();
        #pragma unroll
        for (int kk = 0; kk < 2; ++kk) {
            v8h af[4], bf[4];
            #pragma unroll
            for (int mi = 0; mi < 4; ++mi)
                af[mi] = *(const v8h*)&As[wm * 64 + mi * 16 + l15][kk * 32 + quad * 8];
            #pragma unroll
            for (int ni = 0; ni < 4; ++ni)
                bf[ni] = *(const v8h*)&Bs[wn * 64 + ni * 16 + l15][kk * 32 + quad * 8];
            #pragma unroll
            for (int mi = 0; mi < 4; ++mi)
                #pragma unroll
                for (int ni = 0; ni < 4; ++ni)
                    acc[mi][ni] = __builtin_amdgcn_mfma_f32_16x16x32_f16(
                        af[mi], bf[ni], acc[mi][ni], 0, 0, 0);
        }
    }
    __syncthreads();

    f16 (*Ep)[136] = (f16(*)[136])smem;
    #pragma unroll
    for (int mi = 0; mi < 4; ++mi)
        #pragma unroll
        for (int ni = 0; ni < 4; ++ni)
            #pragma unroll
            for (int r = 0; r < 4; ++r) {
                int ml = wm * 64 + mi * 16 + quad * 4 + r;
                int nl = wn * 64 + ni * 16 + l15;
                f16 val = (f16)acc[mi][ni][r];
                if (z == 2) Ep[nl][ml] = val;
                else        Ep[ml][nl] = val;
            }
    __syncthreads();

    const int b = m0 >> 11, s0 = m0 & 2047, h = n0 >> 7;
    if (z < 2) {
        f16* outp = (z == 0) ? qh : kh;
        const float scl = (z == 0) ? 0.08838834764831845f : 1.0f;
        #pragma unroll
        for (int it = 0; it < 8; ++it) {
            int ch = tid + it * 256, row = ch >> 4, c = ch & 15;
            v8h val = *(const v8h*)&Ep[row][c * 8];
            int s = s0 + row;
            const float* cp = cs + (size_t)s * DHc + c * 8;
            const float* sp = sn + (size_t)s * DHc + c * 8;
            f32x4 ca = *(const f32x4*)cp, cb = *(const f32x4*)(cp + 4);
            f32x4 sa = *(const f32x4*)sp, sb = *(const f32x4*)(sp + 4);
            float v[8];
            #pragma unroll
            for (int j = 0; j < 8; ++j) v[j] = (float)val[j];
            v8h rv;
            rv[0] = (f16)((v[0]*ca[0] - v[1]*sa[0]) * scl);
            rv[1] = (f16)((v[1]*ca[1] + v[0]*sa[1]) * scl);
            rv[2] = (f16)((v[2]*ca[2] - v[3]*sa[2]) * scl);
            rv[3] = (f16)((v[3]*ca[3] + v[2]*sa[3]) * scl);
            rv[4] = (f16)((v[4]*cb[0] - v[5]*sb[0]) * scl);
            rv[5] = (f16)((v[5]*cb[1] + v[4]*sb[1]) * scl);
            rv[6] = (f16)((v[6]*cb[2] - v[7]*sb[2]) * scl);
            rv[7] = (f16)((v[7]*cb[3] + v[6]*sb[3]) * scl);
            *(v8h*)(outp + ((size_t)((b * Hc + h) * Sc) + s0 + row) * DHc + c * 8) = rv;
        }
    } else {
        #pragma unroll
        for (int it = 0; it < 8; ++it) {
            int ch = tid + it * 256, row = ch >> 4, c = ch & 15;
            *(v8h*)(vt + ((size_t)((b * Hc + h) * DHc) + row) * Sc + s0 + c * 8) =
                *(const v8h*)&Ep[row][c * 8];
        }
    }
}

// ---------------------------------------------------------------------------
// Fallback proj (ws too small) + separate rope.
// ---------------------------------------------------------------------------
__launch_bounds__(256)
__global__ void proj_kernel(const float* __restrict__ x, const float* __restrict__ wq,
                            const float* __restrict__ wk, const float* __restrict__ wv,
                            f16* __restrict__ qh, f16* __restrict__ kh, f16* __restrict__ vt)
{
    const int z = blockIdx.z;
    const float* w = (z == 0) ? wq : ((z == 1) ? wk : wv);
    const int m0 = blockIdx.x * 128, n0 = blockIdx.y * 128;
    const int tid = threadIdx.x, lane = tid & 63, wid = tid >> 6;
    const int wm = wid >> 1, wn = wid & 1;
    const int l15 = lane & 15, quad = lane >> 4;

    __shared__ __align__(16) f16 smem[2 * 128 * 72];
    f16 (*As)[72] = (f16(*)[72])smem;
    f16 (*Bs)[72] = (f16(*)[72])(smem + 128 * 72);

    v4f acc[4][4];
    for (int i = 0; i < 4; ++i)
        for (int j = 0; j < 4; ++j)
            acc[i][j] = (v4f){0.f, 0.f, 0.f, 0.f};

    for (int k0 = 0; k0 < Dc; k0 += 64) {
        __syncthreads();
        for (int it = 0; it < 4; ++it) {
            int chunk = tid + it * 256;
            int r = chunk >> 3, cc = chunk & 7;
            const f32x4* pa = (const f32x4*)(x + (size_t)(m0 + r) * Dc + k0 + cc * 8);
            f32x4 a0 = pa[0], a1 = pa[1];
            v8h ha;
            ha[0]=(f16)a0[0]; ha[1]=(f16)a0[1]; ha[2]=(f16)a0[2]; ha[3]=(f16)a0[3];
            ha[4]=(f16)a1[0]; ha[5]=(f16)a1[1]; ha[6]=(f16)a1[2]; ha[7]=(f16)a1[3];
            *(v8h*)&As[r][cc * 8] = ha;
            const f32x4* pb = (const f32x4*)(w + (size_t)(n0 + r) * Dc + k0 + cc * 8);
            f32x4 b0 = pb[0], b1 = pb[1];
            v8h hb;
            hb[0]=(f16)b0[0]; hb[1]=(f16)b0[1]; hb[2]=(f16)b0[2]; hb[3]=(f16)b0[3];
            hb[4]=(f16)b1[0]; hb[5]=(f16)b1[1]; hb[6]=(f16)b1[2]; hb[7]=(f16)b1[3];
            *(v8h*)&Bs[r][cc * 8] = hb;
        }
        __syncthreads();
        for (int kk = 0; kk < 2; ++kk) {
            v8h af[4], bf[4];
            for (int mi = 0; mi < 4; ++mi)
                af[mi] = *(const v8h*)&As[wm * 64 + mi * 16 + l15][kk * 32 + quad * 8];
            for (int ni = 0; ni < 4; ++ni)
                bf[ni] = *(const v8h*)&Bs[wn * 64 + ni * 16 + l15][kk * 32 + quad * 8];
            for (int mi = 0; mi < 4; ++mi)
                for (int ni = 0; ni < 4; ++ni)
                    acc[mi][ni] = __builtin_amdgcn_mfma_f32_16x16x32_f16(
                        af[mi], bf[ni], acc[mi][ni], 0, 0, 0);
        }
    }
    __syncthreads();
    f16 (*Ep)[136] = (f16(*)[136])smem;
    for (int mi = 0; mi < 4; ++mi)
        for (int ni = 0; ni < 4; ++ni)
            for (int r = 0; r < 4; ++r) {
                int ml = wm * 64 + mi * 16 + quad * 4 + r;
                int nl = wn * 64 + ni * 16 + l15;
                f16 val = (f16)acc[mi][ni][r];
                if (z == 2) Ep[nl][ml] = val;
                else        Ep[ml][nl] = val;
            }
    __syncthreads();
    const int b = m0 >> 11, s0 = m0 & 2047, h = n0 >> 7;
    if (z < 2) {
        f16* outp = (z == 0) ? qh : kh;
        for (int it = 0; it < 8; ++it) {
            int ch = tid + it * 256, row = ch >> 4, c = ch & 15;
            *(v8h*)(outp + ((size_t)((b * Hc + h) * Sc) + s0 + row) * DHc + c * 8) =
                *(const v8h*)&Ep[row][c * 8];
        }
    } else {
        for (int it = 0; it < 8; ++it) {
            int ch = tid + it * 256, row = ch >> 4, c = ch & 15;
            *(v8h*)(vt + ((size_t)((b * Hc + h) * DHc) + row) * Sc + s0 + c * 8) =
                *(const v8h*)&Ep[row][c * 8];
        }
    }
}

__global__ void rope_kernel(f16* __restrict__ qh, f16* __restrict__ kh,
                            const float* __restrict__ cs, const float* __restrict__ sn)
{
    int i  = blockIdx.x * 256 + threadIdx.x;
    int d2 = i & 63;
    int s  = (i >> 6) & (Sc - 1);
    int bh = i >> 17;
    f16* t = blockIdx.y ? kh : qh;
    float scale = blockIdx.y ? 1.0f : 0.08838834764831845f;
    float c  = cs[s * DHc + 2 * d2];
    float sv = sn[s * DHc + 2 * d2];
    f16* p = t + ((size_t)bh * Sc + s) * DHc + 2 * d2;
    float t0 = (float)p[0], t1 = (float)p[1];
    p[0] = (f16)((t0 * c - t1 * sv) * scale);
    p[1] = (f16)((t1 * c + t0 * sv) * scale);
}

// ---------------------------------------------------------------------------
// Flash attention v5: K fragments straight from GLOBAL (L1 absorbs the 4x
// intra-block reuse: one wave consumes all 16 chunks of each 256B K-row in
// one iteration). Only V lives in LDS (32 KB dbuf, async global_load_lds,
// XOR-swizzled source). 3 blocks/CU. Fixed-max softmax. Paired-lane f32x4
// stores (32B-contiguous per row-pair).
// ---------------------------------------------------------------------------
__launch_bounds__(256, 3)
__global__ void attn_kernel(const f16* __restrict__ qh, const f16* __restrict__ kh,
                            const f16* __restrict__ vt, float* __restrict__ out)
{
    const int qt = 15 - blockIdx.x;
    const int bh = blockIdx.y;
    const int b = bh >> 4, h = bh & 15;
    const int tid = threadIdx.x, lane = tid & 63, w = tid >> 6;
    const int l31 = lane & 31, half = lane >> 5;

    __shared__ __align__(16) f16 vsm[2 * 8192];   // V dbuf only: 32 KB

    const int q0 = qt * 128 + w * 32;
    const int qg = q0 + l31;
    const size_t bhoff = (size_t)bh * Sc * DHc;

    // Q as B-operand frags (dh step s covers 16s..16s+15)
    v8h qf[8];
    const f16* qrow = qh + bhoff + (size_t)qg * DHc;
    #pragma unroll
    for (int s = 0; s < 8; ++s)
        qf[s] = *(const v8h*)(qrow + s * 16 + half * 8);

    // K global bases for this lane (row l31 / 32+l31, chunk = s*16 + half*8)
    const f16* kb0 = kh + bhoff + (size_t)l31 * DHc + half * 8;
    const f16* kb1 = kb0 + 32 * DHc;

    // V staging: r = w*8 + (lane>>3) + 32j, c = (lane&7) ^ ((lane>>3)&7)
    const int vr = w * 8 + (lane >> 3);
    const int vc = (lane & 7) ^ ((lane >> 3) & 7);
    const f16* vsrc0 = vt + bhoff + (size_t)vr * Sc + vc * 8;
    const int vdst0 = (w * 64) * 8;               // halves; lane*16B implicit

#define STAGEV(kt_, buf_) do {                                                     \
        _Pragma("unroll")                                                          \
        for (int j = 0; j < 4; ++j) {                                              \
            __builtin_amdgcn_global_load_lds(                                      \
                (const __attribute__((address_space(1))) void*)                    \
                    (vsrc0 + (size_t)(j * 32) * Sc + (kt_) * 64),                  \
                (__attribute__((address_space(3))) void*)                          \
                    (vsm + (buf_) * 8192 + vdst0 + j * 2048), 16, 0, 0);           \
        } } while (0)

    float l_run = 0.f;
    v16f o[4];
    #pragma unroll
    for (int i = 0; i < 4; ++i)
        #pragma unroll
        for (int r = 0; r < 16; ++r) o[i][r] = 0.f;

    const int sw = l31 & 7;
    const int nkt = 2 * qt + 2;

    STAGEV(0, 0);
    for (int kt = 0; kt < nkt; ++kt) {
        __syncthreads();                 // publishes V buf[kt&1]
        const int buf = kt & 1;
        if (kt + 1 < nkt) STAGEV(kt + 1, buf ^ 1);
        if (q0 + 31 < kt * 64) continue;

        const f16* vbuf = vsm + buf * 8192;
        const bool do1 = (kt * 64 + 32 <= q0 + 31);
        const f16* k0p = kb0 + (size_t)kt * 64 * DHc;
        const f16* k1p = kb1 + (size_t)kt * 64 * DHc;

        v16f st0, st1;
        #pragma unroll
        for (int r = 0; r < 16; ++r) { st0[r] = 0.f; st1[r] = 0.f; }
        #pragma unroll
        for (int s = 0; s < 8; ++s) {
            v8h kf0 = *(const v8h*)(k0p + s * 16);
            st0 = __builtin_amdgcn_mfma_f32_32x32x16_f16(kf0, qf[s], st0, 0, 0, 0);
            if (do1) {
                v8h kf1 = *(const v8h*)(k1p + s * 16);
                st1 = __builtin_amdgcn_mfma_f32_32x32x16_f16(kf1, qf[s], st1, 0, 0, 0);
            }
        }

        // mask + exp (fixed max) + row-sum
        float sum = 0.f;
        #pragma unroll
        for (int r = 0; r < 16; ++r) {
            int key = kt * 64 + (r & 3) + 8 * (r >> 2) + 4 * half;
            float sv = (key > qg) ? -1e30f : st0[r];
            float p = __expf(sv);
            st0[r] = p; sum += p;
        }
        if (do1) {
            #pragma unroll
            for (int r = 0; r < 16; ++r) {
                int key = kt * 64 + 32 + (r & 3) + 8 * (r >> 2) + 4 * half;
                float sv = (key > qg) ? -1e30f : st1[r];
                float p = __expf(sv);
                st1[r] = p; sum += p;
            }
        }
        sum += __shfl_xor(sum, 32);
        l_run += sum;

        // O^T += V^T . P^T (P^T straight from registers)
        #pragma unroll
        for (int s2 = 0; s2 < 4; ++s2) {
            v4h bfr;
            bfr[0]=(f16)st0[4*s2]; bfr[1]=(f16)st0[4*s2+1];
            bfr[2]=(f16)st0[4*s2+2]; bfr[3]=(f16)st0[4*s2+3];
            int c = ((s2 ^ sw) * 8) + half * 4;
            #pragma unroll
            for (int dt = 0; dt < 4; ++dt) {
                v4h vf = *(const v4h*)(vbuf + (dt * 32 + l31) * 64 + c);
                o[dt] = __builtin_amdgcn_mfma_f32_32x32x8f16(vf, bfr, o[dt], 0, 0, 0);
            }
        }
        if (do1) {
            #pragma unroll
            for (int s2 = 0; s2 < 4; ++s2) {
                v4h bfr;
                bfr[0]=(f16)st1[4*s2]; bfr[1]=(f16)st1[4*s2+1];
                bfr[2]=(f16)st1[4*s2+2]; bfr[3]=(f16)st1[4*s2+3];
                int c = (((4 + s2) ^ sw) * 8) + half * 4;
                #pragma unroll
                for (int dt = 0; dt < 4; ++dt) {
                    v4h vf = *(const v4h*)(vbuf + (dt * 32 + l31) * 64 + c);
                    o[dt] = __builtin_amdgcn_mfma_f32_32x32x8f16(vf, bfr, o[dt], 0, 0, 0);
                }
            }
        }
    }
#undef STAGEV

    // normalize + softmax over Dh (64 in-lane + partner half)
    float inv = 1.f / l_run;
    float mxd = -1e30f;
    #pragma unroll
    for (int dt = 0; dt < 4; ++dt)
        #pragma unroll
        for (int r = 0; r < 16; ++r) {
            o[dt][r] *= inv;
            mxd = fmaxf(mxd, o[dt][r]);
        }
    mxd = fmaxf(mxd, __shfl_xor(mxd, 32));
    float sd = 0.f;
    #pragma unroll
    for (int dt = 0; dt < 4; ++dt)
        #pragma unroll
        for (int r = 0; r < 16; ++r) {
            float t = __expf(o[dt][r] - mxd);
            o[dt][r] = t;
            sd += t;
        }
    sd += __shfl_xor(sd, 32);
    float rinv = 1.f / sd;

    // paired-lane contiguous stores: regs 4g..4g+3 = dh dt*32+8g+4*half+{0..3}
    float* orow = out + (size_t)(b * Sc + qg) * Dc + h * DHc;
    #pragma unroll
    for (int dt = 0; dt < 4; ++dt)
        #pragma unroll
        for (int g = 0; g < 4; ++g) {
            f32x4 vv;
            vv[0] = o[dt][4*g+0] * rinv;
            vv[1] = o[dt][4*g+1] * rinv;
            vv[2] = o[dt][4*g+2] * rinv;
            vv[3] = o[dt][4*g+3] * rinv;
            *(f32x4*)(orow + dt * 32 + g * 8 + half * 4) = vv;
        }
}

extern "C" void kernel_launch(void* const* d_in, const int* in_sizes, int n_in,
                              void* d_out, int out_size, void* d_ws, size_t ws_size,
                              hipStream_t stream)
{
    const float* x  = (const float*)d_in[0];
    const float* wq = (const float*)d_in[1];
    const float* wk = (const float*)d_in[2];
    const float* wv = (const float*)d_in[3];
    const float* cs = (const float*)d_in[4];
    const float* sn = (const float*)d_in[5];
    float* out = (float*)d_out;

    const size_t tsz = (size_t)Bc * Hc * Sc * DHc;   // 8,388,608 halves
    f16* qh = (f16*)d_ws;
    f16* kh = qh + tsz;
    f16* vt = kh + tsz;

    if (ws_size >= 11 * tsz) {
        f16* xh  = vt + tsz;
        f16* wqh = xh + tsz;
        f16* wkh = wqh + tsz / 2;
        f16* wvh = wkh + tsz / 2;
        cvt_kernel<<<20480, 256, 0, stream>>>(x, wq, wk, wv, xh, wqh, wkh, wvh);
        proj_f16_kernel<<<dim3(32, 16, 3), 256, 0, stream>>>(xh, wqh, wkh, wvh,
                                                             cs, sn, qh, kh, vt);
    } else {
        proj_kernel<<<dim3(32, 16, 3), 256, 0, stream>>>(x, wq, wk, wv, qh, kh, vt);
        rope_kernel<<<dim3(16384, 2), 256, 0, stream>>>(qh, kh, cs, sn);
    }
    attn_kernel<<<dim3(16, 32), 256, 0, stream>>>(qh, kh, vt, out);
}

// Round 5
// 356.301 us; speedup vs baseline: 1.2994x; 1.2994x over previous
//
#include <hip/hip_runtime.h>

#define Bc 2
#define Sc 2048
#define Dc 2048
#define Hc 16
#define DHc 128

typedef _Float16 f16;
typedef __attribute__((ext_vector_type(4))) _Float16 v4h;
typedef __attribute__((ext_vector_type(8))) _Float16 v8h;
typedef __attribute__((ext_vector_type(4))) float v4f;
typedef __attribute__((ext_vector_type(16))) float v16f;
typedef __attribute__((ext_vector_type(4))) float f32x4;

// ---------------------------------------------------------------------------
// Convert f32 inputs -> f16 once.
// ---------------------------------------------------------------------------
__global__ void cvt_kernel(const float* __restrict__ x, const float* __restrict__ wq,
                           const float* __restrict__ wk, const float* __restrict__ wv,
                           f16* __restrict__ xh, f16* __restrict__ wqh,
                           f16* __restrict__ wkh, f16* __restrict__ wvh)
{
    int bid = blockIdx.x;
    const float* src; f16* dst; int idx;
    if (bid < 8192)       { src = x;  dst = xh;  idx = bid; }
    else if (bid < 12288) { src = wq; dst = wqh; idx = bid - 8192; }
    else if (bid < 16384) { src = wk; dst = wkh; idx = bid - 12288; }
    else                  { src = wv; dst = wvh; idx = bid - 16384; }
    int i = idx * 256 + threadIdx.x;
    f32x4 v = ((const f32x4*)src)[i];
    v4h hv; hv[0]=(f16)v[0]; hv[1]=(f16)v[1]; hv[2]=(f16)v[2]; hv[3]=(f16)v[3];
    ((v4h*)dst)[i] = hv;
}

// ---------------------------------------------------------------------------
// f16 projection GEMM (global_load_lds width=16) with RoPE fused into the
// epilogue for z<2. z: 0->Q (roped+scaled), 1->K (roped), 2->V^T [dh][s].
// ---------------------------------------------------------------------------
__launch_bounds__(256)
__global__ void proj_f16_kernel(const f16* __restrict__ xh, const f16* __restrict__ wqh,
                                const f16* __restrict__ wkh, const f16* __restrict__ wvh,
                                const float* __restrict__ cs, const float* __restrict__ sn,
                                f16* __restrict__ qh, f16* __restrict__ kh,
                                f16* __restrict__ vt)
{
    const int z = blockIdx.z;
    const f16* wh = (z == 0) ? wqh : ((z == 1) ? wkh : wvh);
    const int m0 = blockIdx.x * 128, n0 = blockIdx.y * 128;
    const int tid = threadIdx.x, lane = tid & 63, wid = tid >> 6;
    const int wm = wid >> 1, wn = wid & 1;
    const int l15 = lane & 15, quad = lane >> 4;
    const int lrow = lane >> 3, lcol = lane & 7;

    __shared__ __align__(16) f16 smem[128 * 136];
    f16 (*As)[64] = (f16(*)[64])smem;
    f16 (*Bs)[64] = (f16(*)[64])(smem + 8192);

    v4f acc[4][4];
    #pragma unroll
    for (int i = 0; i < 4; ++i)
        #pragma unroll
        for (int j = 0; j < 4; ++j)
            acc[i][j] = (v4f){0.f, 0.f, 0.f, 0.f};

    for (int k0 = 0; k0 < Dc; k0 += 64) {
        __syncthreads();
        #pragma unroll
        for (int i = 0; i < 4; ++i) {
            int g = wid * 4 + i;
            const f16* ga = xh + (size_t)(m0 + g * 8 + lrow) * Dc + k0 + lcol * 8;
            __builtin_amdgcn_global_load_lds(
                (const __attribute__((address_space(1))) void*)ga,
                (__attribute__((address_space(3))) void*)(smem + g * 512), 16, 0, 0);
            const f16* gb = wh + (size_t)(n0 + g * 8 + lrow) * Dc + k0 + lcol * 8;
            __builtin_amdgcn_global_load_lds(
                (const __attribute__((address_space(1))) void*)gb,
                (__attribute__((address_space(3))) void*)(smem + 8192 + g * 512), 16, 0, 0);
        }
        __syncthreads();
        #pragma unroll
        for (int kk = 0; kk < 2; ++kk) {
            v8h af[4], bf[4];
            #pragma unroll
            for (int mi = 0; mi < 4; ++mi)
                af[mi] = *(const v8h*)&As[wm * 64 + mi * 16 + l15][kk * 32 + quad * 8];
            #pragma unroll
            for (int ni = 0; ni < 4; ++ni)
                bf[ni] = *(const v8h*)&Bs[wn * 64 + ni * 16 + l15][kk * 32 + quad * 8];
            #pragma unroll
            for (int mi = 0; mi < 4; ++mi)
                #pragma unroll
                for (int ni = 0; ni < 4; ++ni)
                    acc[mi][ni] = __builtin_amdgcn_mfma_f32_16x16x32_f16(
                        af[mi], bf[ni], acc[mi][ni], 0, 0, 0);
        }
    }
    __syncthreads();

    f16 (*Ep)[136] = (f16(*)[136])smem;
    #pragma unroll
    for (int mi = 0; mi < 4; ++mi)
        #pragma unroll
        for (int ni = 0; ni < 4; ++ni)
            #pragma unroll
            for (int r = 0; r < 4; ++r) {
                int ml = wm * 64 + mi * 16 + quad * 4 + r;
                int nl = wn * 64 + ni * 16 + l15;
                f16 val = (f16)acc[mi][ni][r];
                if (z == 2) Ep[nl][ml] = val;
                else        Ep[ml][nl] = val;
            }
    __syncthreads();

    const int b = m0 >> 11, s0 = m0 & 2047, h = n0 >> 7;
    if (z < 2) {
        f16* outp = (z == 0) ? qh : kh;
        const float scl = (z == 0) ? 0.08838834764831845f : 1.0f;
        #pragma unroll
        for (int it = 0; it < 8; ++it) {
            int ch = tid + it * 256, row = ch >> 4, c = ch & 15;
            v8h val = *(const v8h*)&Ep[row][c * 8];
            int s = s0 + row;
            const float* cp = cs + (size_t)s * DHc + c * 8;
            const float* sp = sn + (size_t)s * DHc + c * 8;
            f32x4 ca = *(const f32x4*)cp, cb = *(const f32x4*)(cp + 4);
            f32x4 sa = *(const f32x4*)sp, sb = *(const f32x4*)(sp + 4);
            float v[8];
            #pragma unroll
            for (int j = 0; j < 8; ++j) v[j] = (float)val[j];
            v8h rv;
            rv[0] = (f16)((v[0]*ca[0] - v[1]*sa[0]) * scl);
            rv[1] = (f16)((v[1]*ca[1] + v[0]*sa[1]) * scl);
            rv[2] = (f16)((v[2]*ca[2] - v[3]*sa[2]) * scl);
            rv[3] = (f16)((v[3]*ca[3] + v[2]*sa[3]) * scl);
            rv[4] = (f16)((v[4]*cb[0] - v[5]*sb[0]) * scl);
            rv[5] = (f16)((v[5]*cb[1] + v[4]*sb[1]) * scl);
            rv[6] = (f16)((v[6]*cb[2] - v[7]*sb[2]) * scl);
            rv[7] = (f16)((v[7]*cb[3] + v[6]*sb[3]) * scl);
            *(v8h*)(outp + ((size_t)((b * Hc + h) * Sc) + s0 + row) * DHc + c * 8) = rv;
        }
    } else {
        #pragma unroll
        for (int it = 0; it < 8; ++it) {
            int ch = tid + it * 256, row = ch >> 4, c = ch & 15;
            *(v8h*)(vt + ((size_t)((b * Hc + h) * DHc) + row) * Sc + s0 + c * 8) =
                *(const v8h*)&Ep[row][c * 8];
        }
    }
}

// ---------------------------------------------------------------------------
// Fallback proj (ws too small) + separate rope.
// ---------------------------------------------------------------------------
__launch_bounds__(256)
__global__ void proj_kernel(const float* __restrict__ x, const float* __restrict__ wq,
                            const float* __restrict__ wk, const float* __restrict__ wv,
                            f16* __restrict__ qh, f16* __restrict__ kh, f16* __restrict__ vt)
{
    const int z = blockIdx.z;
    const float* w = (z == 0) ? wq : ((z == 1) ? wk : wv);
    const int m0 = blockIdx.x * 128, n0 = blockIdx.y * 128;
    const int tid = threadIdx.x, lane = tid & 63, wid = tid >> 6;
    const int wm = wid >> 1, wn = wid & 1;
    const int l15 = lane & 15, quad = lane >> 4;

    __shared__ __align__(16) f16 smem[2 * 128 * 72];
    f16 (*As)[72] = (f16(*)[72])smem;
    f16 (*Bs)[72] = (f16(*)[72])(smem + 128 * 72);

    v4f acc[4][4];
    for (int i = 0; i < 4; ++i)
        for (int j = 0; j < 4; ++j)
            acc[i][j] = (v4f){0.f, 0.f, 0.f, 0.f};

    for (int k0 = 0; k0 < Dc; k0 += 64) {
        __syncthreads();
        for (int it = 0; it < 4; ++it) {
            int chunk = tid + it * 256;
            int r = chunk >> 3, cc = chunk & 7;
            const f32x4* pa = (const f32x4*)(x + (size_t)(m0 + r) * Dc + k0 + cc * 8);
            f32x4 a0 = pa[0], a1 = pa[1];
            v8h ha;
            ha[0]=(f16)a0[0]; ha[1]=(f16)a0[1]; ha[2]=(f16)a0[2]; ha[3]=(f16)a0[3];
            ha[4]=(f16)a1[0]; ha[5]=(f16)a1[1]; ha[6]=(f16)a1[2]; ha[7]=(f16)a1[3];
            *(v8h*)&As[r][cc * 8] = ha;
            const f32x4* pb = (const f32x4*)(w + (size_t)(n0 + r) * Dc + k0 + cc * 8);
            f32x4 b0 = pb[0], b1 = pb[1];
            v8h hb;
            hb[0]=(f16)b0[0]; hb[1]=(f16)b0[1]; hb[2]=(f16)b0[2]; hb[3]=(f16)b0[3];
            hb[4]=(f16)b1[0]; hb[5]=(f16)b1[1]; hb[6]=(f16)b1[2]; hb[7]=(f16)b1[3];
            *(v8h*)&Bs[r][cc * 8] = hb;
        }
        __syncthreads();
        for (int kk = 0; kk < 2; ++kk) {
            v8h af[4], bf[4];
            for (int mi = 0; mi < 4; ++mi)
                af[mi] = *(const v8h*)&As[wm * 64 + mi * 16 + l15][kk * 32 + quad * 8];
            for (int ni = 0; ni < 4; ++ni)
                bf[ni] = *(const v8h*)&Bs[wn * 64 + ni * 16 + l15][kk * 32 + quad * 8];
            for (int mi = 0; mi < 4; ++mi)
                for (int ni = 0; ni < 4; ++ni)
                    acc[mi][ni] = __builtin_amdgcn_mfma_f32_16x16x32_f16(
                        af[mi], bf[ni], acc[mi][ni], 0, 0, 0);
        }
    }
    __syncthreads();
    f16 (*Ep)[136] = (f16(*)[136])smem;
    for (int mi = 0; mi < 4; ++mi)
        for (int ni = 0; ni < 4; ++ni)
            for (int r = 0; r < 4; ++r) {
                int ml = wm * 64 + mi * 16 + quad * 4 + r;
                int nl = wn * 64 + ni * 16 + l15;
                f16 val = (f16)acc[mi][ni][r];
                if (z == 2) Ep[nl][ml] = val;
                else        Ep[ml][nl] = val;
            }
    __syncthreads();
    const int b = m0 >> 11, s0 = m0 & 2047, h = n0 >> 7;
    if (z < 2) {
        f16* outp = (z == 0) ? qh : kh;
        for (int it = 0; it < 8; ++it) {
            int ch = tid + it * 256, row = ch >> 4, c = ch & 15;
            *(v8h*)(outp + ((size_t)((b * Hc + h) * Sc) + s0 + row) * DHc + c * 8) =
                *(const v8h*)&Ep[row][c * 8];
        }
    } else {
        for (int it = 0; it < 8; ++it) {
            int ch = tid + it * 256, row = ch >> 4, c = ch & 15;
            *(v8h*)(vt + ((size_t)((b * Hc + h) * DHc) + row) * Sc + s0 + c * 8) =
                *(const v8h*)&Ep[row][c * 8];
        }
    }
}

__global__ void rope_kernel(f16* __restrict__ qh, f16* __restrict__ kh,
                            const float* __restrict__ cs, const float* __restrict__ sn)
{
    int i  = blockIdx.x * 256 + threadIdx.x;
    int d2 = i & 63;
    int s  = (i >> 6) & (Sc - 1);
    int bh = i >> 17;
    f16* t = blockIdx.y ? kh : qh;
    float scale = blockIdx.y ? 1.0f : 0.08838834764831845f;
    float c  = cs[s * DHc + 2 * d2];
    float sv = sn[s * DHc + 2 * d2];
    f16* p = t + ((size_t)bh * Sc + s) * DHc + 2 * d2;
    float t0 = (float)p[0], t1 = (float)p[1];
    p[0] = (f16)((t0 * c - t1 * sv) * scale);
    p[1] = (f16)((t1 * c + t0 * sv) * scale);
}

// ---------------------------------------------------------------------------
// Flash attention v6: balanced + XCD-local.
//  - Each block processes query-tiles {15-p, p}: exactly 34 KV-iters/block.
//    Grid = 256 blocks (1/CU), no tail imbalance (fixes Occupancy~10% stall).
//  - XCD swizzle: bh = (blockIdx&7)*4 + (slot>>3) -> the 8 blocks sharing a bh
//    sit on one XCD; K+V (1 MB x 4 bh) fits its 4 MB L2 -> staging = L2 hits.
//  - K+V in LDS (r4's K-from-global refetched 110 MB from HBM - reverted),
//    async global_load_lds dbuf, XOR-swizzled source, single barrier/iter.
//  - Fixed-max softmax; direct paired-lane stores (no write amplification).
// ---------------------------------------------------------------------------
__launch_bounds__(256, 2)
__global__ void attn_kernel(const f16* __restrict__ qh, const f16* __restrict__ kh,
                            const f16* __restrict__ vt, float* __restrict__ out)
{
    const int L = blockIdx.x;
    const int slot = L >> 3;
    const int bh = (L & 7) * 4 + (slot >> 3);
    const int p  = slot & 7;
    const int b = bh >> 4, h = bh & 15;
    const int tid = threadIdx.x, lane = tid & 63, w = tid >> 6;
    const int l31 = lane & 31, half = lane >> 5;
    const int sw = l31 & 7;

    __shared__ __align__(16) f16 smem[32768];     // K dbuf 32KB + V dbuf 32KB
    f16* ksm = smem;
    f16* vsm = smem + 16384;

    const size_t bhoff = (size_t)bh * Sc * DHc;

    // staging bases (swizzled global source, lane-linear LDS dest) — as r3
    const f16* ksrc[4]; const f16* vsrc[4];
    f16* kdst[4]; f16* vdst[4];
    #pragma unroll
    for (int j = 0; j < 4; ++j) {
        int slot0 = j * 256 + w * 64;
        {   int r = (slot0 >> 4) + (lane >> 4);
            int c = (lane & 15) ^ (r & 7);
            ksrc[j] = kh + bhoff + (size_t)r * DHc + c * 8;
            kdst[j] = ksm + slot0 * 8; }
        {   int r = (slot0 >> 3) + (lane >> 3);
            int c = (lane & 7) ^ (r & 7);
            vsrc[j] = vt + bhoff + (size_t)r * Sc + c * 8;
            vdst[j] = vsm + slot0 * 8; }
    }

#define STAGE(kt_, buf_) do {                                                   \
        int _ko = (kt_) * 64 * DHc;                                             \
        int _vo = (kt_) * 64;                                                   \
        int _lb = (buf_) * 8192;                                                \
        _Pragma("unroll")                                                       \
        for (int j = 0; j < 4; ++j) {                                           \
            __builtin_amdgcn_global_load_lds(                                   \
                (const __attribute__((address_space(1))) void*)(ksrc[j] + _ko), \
                (__attribute__((address_space(3))) void*)(kdst[j] + _lb), 16, 0, 0); \
            __builtin_amdgcn_global_load_lds(                                   \
                (const __attribute__((address_space(1))) void*)(vsrc[j] + _vo), \
                (__attribute__((address_space(3))) void*)(vdst[j] + _lb), 16, 0, 0); \
        } } while (0)

    const int qtA = 15 - p;
    const int nktA = 2 * qtA + 2;     // + nktB = 34 for every block

    int ibuf = 0;
    STAGE(0, 0);

    #pragma unroll 1
    for (int ph = 0; ph < 2; ++ph) {
        const int qt  = ph ? p : qtA;
        const int nkt = 2 * qt + 2;
        const int q0  = qt * 128 + w * 32;
        const int qg  = q0 + l31;

        // Q as B-operand frags (dh step s covers 16s..16s+15)
        v8h qf[8];
        const f16* qrow = qh + bhoff + (size_t)qg * DHc;
        #pragma unroll
        for (int s = 0; s < 8; ++s)
            qf[s] = *(const v8h*)(qrow + s * 16 + half * 8);

        float l_run = 0.f;
        v16f o[4];
        #pragma unroll
        for (int i = 0; i < 4; ++i)
            #pragma unroll
            for (int r = 0; r < 16; ++r) o[i][r] = 0.f;

        #pragma unroll 1
        for (int kt = 0; kt < nkt; ++kt, ++ibuf) {
            __syncthreads();             // publishes buf[ibuf&1]
            const int buf = ibuf & 1;
            const int ni = ibuf + 1;
            if (ni < 34) {
                int tn = (ni < nktA) ? ni : ni - nktA;
                STAGE(tn, ni & 1);
            }
            if (q0 + 31 < kt * 64) continue;   // fully masked; barriers uniform

            const f16* kbuf = ksm + buf * 8192;
            const f16* vbuf = vsm + buf * 8192;
            const bool do1 = (kt * 64 + 32 <= q0 + 31);

            v16f st0, st1;
            #pragma unroll
            for (int r = 0; r < 16; ++r) { st0[r] = 0.f; st1[r] = 0.f; }
            #pragma unroll
            for (int s = 0; s < 8; ++s) {
                int c = ((s * 2 + half) ^ sw) * 8;
                v8h kf0 = *(const v8h*)(kbuf + l31 * 128 + c);
                st0 = __builtin_amdgcn_mfma_f32_32x32x16_f16(kf0, qf[s], st0, 0, 0, 0);
                if (do1) {
                    v8h kf1 = *(const v8h*)(kbuf + (32 + l31) * 128 + c);
                    st1 = __builtin_amdgcn_mfma_f32_32x32x16_f16(kf1, qf[s], st1, 0, 0, 0);
                }
            }

            float sum = 0.f;
            #pragma unroll
            for (int r = 0; r < 16; ++r) {
                int key = kt * 64 + (r & 3) + 8 * (r >> 2) + 4 * half;
                float sv = (key > qg) ? -1e30f : st0[r];
                float pe = __expf(sv);
                st0[r] = pe; sum += pe;
            }
            if (do1) {
                #pragma unroll
                for (int r = 0; r < 16; ++r) {
                    int key = kt * 64 + 32 + (r & 3) + 8 * (r >> 2) + 4 * half;
                    float sv = (key > qg) ? -1e30f : st1[r];
                    float pe = __expf(sv);
                    st1[r] = pe; sum += pe;
                }
            }
            sum += __shfl_xor(sum, 32);
            l_run += sum;

            // O^T += V^T . P^T (P^T straight from registers)
            #pragma unroll
            for (int s2 = 0; s2 < 4; ++s2) {
                v4h bfr;
                bfr[0]=(f16)st0[4*s2]; bfr[1]=(f16)st0[4*s2+1];
                bfr[2]=(f16)st0[4*s2+2]; bfr[3]=(f16)st0[4*s2+3];
                int c = ((s2 ^ sw) * 8) + half * 4;
                #pragma unroll
                for (int dt = 0; dt < 4; ++dt) {
                    v4h vf = *(const v4h*)(vbuf + (dt * 32 + l31) * 64 + c);
                    o[dt] = __builtin_amdgcn_mfma_f32_32x32x8f16(vf, bfr, o[dt], 0, 0, 0);
                }
            }
            if (do1) {
                #pragma unroll
                for (int s2 = 0; s2 < 4; ++s2) {
                    v4h bfr;
                    bfr[0]=(f16)st1[4*s2]; bfr[1]=(f16)st1[4*s2+1];
                    bfr[2]=(f16)st1[4*s2+2]; bfr[3]=(f16)st1[4*s2+3];
                    int c = (((4 + s2) ^ sw) * 8) + half * 4;
                    #pragma unroll
                    for (int dt = 0; dt < 4; ++dt) {
                        v4h vf = *(const v4h*)(vbuf + (dt * 32 + l31) * 64 + c);
                        o[dt] = __builtin_amdgcn_mfma_f32_32x32x8f16(vf, bfr, o[dt], 0, 0, 0);
                    }
                }
            }
        }

        // epilogue: normalize + softmax over Dh + paired-lane stores
        float inv = 1.f / l_run;
        float mxd = -1e30f;
        #pragma unroll
        for (int dt = 0; dt < 4; ++dt)
            #pragma unroll
            for (int r = 0; r < 16; ++r) {
                o[dt][r] *= inv;
                mxd = fmaxf(mxd, o[dt][r]);
            }
        mxd = fmaxf(mxd, __shfl_xor(mxd, 32));
        float sd = 0.f;
        #pragma unroll
        for (int dt = 0; dt < 4; ++dt)
            #pragma unroll
            for (int r = 0; r < 16; ++r) {
                float t = __expf(o[dt][r] - mxd);
                o[dt][r] = t;
                sd += t;
            }
        sd += __shfl_xor(sd, 32);
        float rinv = 1.f / sd;

        float* orow = out + (size_t)(b * Sc + qg) * Dc + h * DHc;
        #pragma unroll
        for (int dt = 0; dt < 4; ++dt)
            #pragma unroll
            for (int g = 0; g < 4; ++g) {
                f32x4 vv;
                vv[0] = o[dt][4*g+0] * rinv;
                vv[1] = o[dt][4*g+1] * rinv;
                vv[2] = o[dt][4*g+2] * rinv;
                vv[3] = o[dt][4*g+3] * rinv;
                *(f32x4*)(orow + dt * 32 + g * 8 + half * 4) = vv;
            }
    }
#undef STAGE
}

extern "C" void kernel_launch(void* const* d_in, const int* in_sizes, int n_in,
                              void* d_out, int out_size, void* d_ws, size_t ws_size,
                              hipStream_t stream)
{
    const float* x  = (const float*)d_in[0];
    const float* wq = (const float*)d_in[1];
    const float* wk = (const float*)d_in[2];
    const float* wv = (const float*)d_in[3];
    const float* cs = (const float*)d_in[4];
    const float* sn = (const float*)d_in[5];
    float* out = (float*)d_out;

    const size_t tsz = (size_t)Bc * Hc * Sc * DHc;   // 8,388,608 halves
    f16* qh = (f16*)d_ws;
    f16* kh = qh + tsz;
    f16* vt = kh + tsz;

    if (ws_size >= 11 * tsz) {
        f16* xh  = vt + tsz;
        f16* wqh = xh + tsz;
        f16* wkh = wqh + tsz / 2;
        f16* wvh = wkh + tsz / 2;
        cvt_kernel<<<20480, 256, 0, stream>>>(x, wq, wk, wv, xh, wqh, wkh, wvh);
        proj_f16_kernel<<<dim3(32, 16, 3), 256, 0, stream>>>(xh, wqh, wkh, wvh,
                                                             cs, sn, qh, kh, vt);
    } else {
        proj_kernel<<<dim3(32, 16, 3), 256, 0, stream>>>(x, wq, wk, wv, qh, kh, vt);
        rope_kernel<<<dim3(16384, 2), 256, 0, stream>>>(qh, kh, cs, sn);
    }
    attn_kernel<<<256, 256, 0, stream>>>(qh, kh, vt, out);
}